// Round 16
// baseline (199.658 us; speedup 1.0000x reference)
//
#include <hip/hip_runtime.h>
#include <math.h>

#define CDIM 2048
#define HF 24
#define WF 24
#define PIX 576
#define HO 18
#define WO 18
#define NP 324
#define NHEAD 32
#define HD 64
#define NTOK 50
#define NTXT 45
#define OUTD 512
#define NKV 626
#define HJ (NHEAD * NTXT)   // 1440
#define NROWS 640           // padded B rows for K/V: 576 pixels + 50 pos + 14 zero
#define NQROWS 384          // padded B rows for Q: 324 means + 1 pos0 + 59 zero

typedef __attribute__((ext_vector_type(8))) short short8;
typedef __attribute__((ext_vector_type(4))) float f32x4;
typedef __attribute__((address_space(1))) const void as1c_void;
typedef __attribute__((address_space(3))) void as3_void;

__device__ inline unsigned bf16rn(float x) {
    unsigned u = __float_as_uint(x);
    return (u + 0x7FFFu + ((u >> 16) & 1u)) >> 16;
}
__device__ inline float bf16tof(unsigned h) { return __uint_as_float(h << 16); }

// Fragment-tile global layout (ushort element offset): tile (row>>4, k>>5) is
// 512 contiguous ushorts (1KB); global_load_lds reads it as lane*16B bursts.
__device__ inline size_t frag_off(int row, int k) {
    return (size_t)(((row >> 4) * 64 + (k >> 5)) * 512)
         + (size_t)(((k & 31) >> 3) * 128 + (row & 15) * 8 + (k & 7));
}

// ---------------------------------------------------------------------------
// Split the 3 weight matrices into hi/lo bf16, fragment-tile layout.
__global__ __launch_bounds__(256) void split_w_k(
    const float* __restrict__ kw, const float* __restrict__ vw, const float* __restrict__ qw,
    ushort* __restrict__ WhK, ushort* __restrict__ WlK,
    ushort* __restrict__ WhV, ushort* __restrict__ WlV,
    ushort* __restrict__ WhQ, ushort* __restrict__ WlQ) {
    int gw = blockIdx.x * 4 + (threadIdx.x >> 6);   // global tile id, 3*8192 total
    int lane = threadIdx.x & 63;
    int sel = gw >> 13;                             // matrix (8192 tiles each)
    int tl = gw & 8191;
    int m16 = tl >> 6;                              // row-tile (m/16)
    int kt = tl & 63;                               // k-tile (k/32)
    const float* src = sel == 0 ? kw : sel == 1 ? vw : qw;
    ushort* dh = sel == 0 ? WhK : sel == 1 ? WhV : WhQ;
    ushort* dl = sel == 0 ? WlK : sel == 1 ? WlV : WlQ;

    int row = m16 * 16 + (lane & 15);
    int k = kt * 32 + (lane >> 4) * 8;
    const float* sp = src + (size_t)row * CDIM + k;
    float4 a = *(const float4*)sp;
    float4 b = *(const float4*)(sp + 4);
    float xs[8] = {a.x, a.y, a.z, a.w, b.x, b.y, b.z, b.w};
    short8 hv, lv;
#pragma unroll
    for (int i = 0; i < 8; ++i) {
        unsigned hh = bf16rn(xs[i]);
        hv[i] = (short)hh;
        lv[i] = (short)bf16rn(xs[i] - bf16tof(hh));
    }
    size_t to = (size_t)tl * 512 + lane * 8;
    *(short8*)(dh + to) = hv;
    *(short8*)(dl + to) = lv;
}

// ---------------------------------------------------------------------------
// mfeat: per-channel separable 7x7 window mean of feat1 -> mf[c][p] (fp32).
// One block per channel; row + colsum in LDS. (Mean-first matches reference.)
__global__ __launch_bounds__(64) void mfeat_k(const float* __restrict__ feat1,
                                              float* __restrict__ mf) {
    __shared__ float row[PIX];
    __shared__ float cs[24 * 18];
    int c = blockIdx.x, tid = threadIdx.x;
    for (int idx = tid; idx < PIX; idx += 64) row[idx] = feat1[(size_t)c * PIX + idx];
    __syncthreads();
    for (int idx = tid; idx < 24 * 18; idx += 64) {
        int i = idx / 18, j = idx % 18;
        float s = 0.f;
#pragma unroll
        for (int d = 0; d < 7; ++d) s += row[i * 24 + j + d];
        cs[idx] = s;
    }
    __syncthreads();
    for (int idx = tid; idx < NP; idx += 64) {
        int pi = idx / 18, pj = idx % 18;
        float s = 0.f;
#pragma unroll
        for (int d = 0; d < 7; ++d) s += cs[(pi + d) * 18 + pj];
        mf[(size_t)c * NP + idx] = s * (1.f / 49.f);
    }
}

// ---------------------------------------------------------------------------
// Merged split/transpose: blocks [0,288) feat1 -> Xh/Xl rows 0..575;
// [288,416) pos rows -> Xh/Xl rows 576..639; [416,608) mf+pos0 -> Xmh/Xml
// rows 0..383 (row 324 = pos[0], rows >324 = 0).
__global__ __launch_bounds__(256) void splitx_k(const float* __restrict__ feat1,
                                                const float* __restrict__ pos,
                                                const float* __restrict__ mf,
                                                ushort* __restrict__ Xh, ushort* __restrict__ Xl,
                                                ushort* __restrict__ Xmh, ushort* __restrict__ Xml) {
    __shared__ float tile[64][65];
    int b = blockIdx.x, tid = threadIdx.x;
    if (b < 288) {
        int n0 = (b % 9) * 64, c0 = (b / 9) * 64;
#pragma unroll
        for (int i = 0; i < 16; ++i) {
            int idx = tid + i * 256;
            int cc = idx >> 6, nn = idx & 63;
            tile[cc][nn] = feat1[(size_t)(c0 + cc) * PIX + n0 + nn];
        }
        __syncthreads();
#pragma unroll
        for (int i = 0; i < 16; ++i) {
            int idx = tid + i * 256;
            int nn = idx >> 6, cc = idx & 63;
            float x = tile[cc][nn];
            unsigned hh = bf16rn(x);
            size_t fo = frag_off(n0 + nn, c0 + cc);
            Xh[fo] = (ushort)hh;
            Xl[fo] = (ushort)bf16rn(x - bf16tof(hh));
        }
    } else if (b < 416) {
        int g = (b - 288) * 256 + tid;              // 32768 threads, 4 elems each
        int r = g >> 9;                              // 0..63
        int c = (g & 511) * 4;
        float4 v = make_float4(0.f, 0.f, 0.f, 0.f);
        if (r < 50) v = *(const float4*)(pos + (size_t)r * CDIM + c);
        float xs[4] = {v.x, v.y, v.z, v.w};
        ushort h[4], l[4];
#pragma unroll
        for (int i = 0; i < 4; ++i) {
            unsigned hh = bf16rn(xs[i]);
            h[i] = (ushort)hh;
            l[i] = (ushort)bf16rn(xs[i] - bf16tof(hh));
        }
        size_t fo = frag_off(576 + r, c);
        *(ushort4*)(Xh + fo) = make_ushort4(h[0], h[1], h[2], h[3]);
        *(ushort4*)(Xl + fo) = make_ushort4(l[0], l[1], l[2], l[3]);
    } else {
        int bb = b - 416;                            // 192 blocks: 6 n x 32 c
        int n0 = (bb % 6) * 64, c0 = (bb / 6) * 64;
#pragma unroll
        for (int i = 0; i < 16; ++i) {
            int idx = tid + i * 256;
            int cc = idx >> 6, nn = idx & 63;
            int p = n0 + nn;
            float v;
            if (p < NP)       v = mf[(size_t)(c0 + cc) * NP + p];
            else if (p == NP) v = pos[(size_t)0 * CDIM + c0 + cc];
            else              v = 0.f;
            tile[cc][nn] = v;
        }
        __syncthreads();
#pragma unroll
        for (int i = 0; i < 16; ++i) {
            int idx = tid + i * 256;
            int nn = idx >> 6, cc = idx & 63;
            float x = tile[cc][nn];
            unsigned hh = bf16rn(x);
            size_t fo = frag_off(n0 + nn, c0 + cc);
            Xmh[fo] = (ushort)hh;
            Xml[fo] = (ushort)bf16rn(x - bf16tof(hh));
        }
    }
}

// ---------------------------------------------------------------------------
// Split-bf16 MFMA GEMM, 3-buffer depth-2 pipeline, coalesced frag-tile staging
// (round-10 schedule). z=0: K (N=640), z=1: V (N=640), z=2: Q (N=384, means).
#define BUFB 24576
__global__ __launch_bounds__(256, 2) void gemm_bf16_k(
    const ushort* __restrict__ WhK, const ushort* __restrict__ WlK,
    const ushort* __restrict__ WhV, const ushort* __restrict__ WlV,
    const ushort* __restrict__ WhQ, const ushort* __restrict__ WlQ,
    const ushort* __restrict__ Xh, const ushort* __restrict__ Xl,
    const ushort* __restrict__ Xmh, const ushort* __restrict__ Xml,
    const float* __restrict__ k_b, const float* __restrict__ v_b, const float* __restrict__ q_b,
    float* __restrict__ Kbuf, float* __restrict__ Vbuf, float* __restrict__ Qm)
{
    __shared__ char smem[3 * BUFB];   // 72 KB: 3 rotating tile buffers
    int z = blockIdx.z;
    if (z == 2 && blockIdx.y >= 6) return;           // Q has only 384 rows
    const ushort* Wh = z == 0 ? WhK : z == 1 ? WhV : WhQ;
    const ushort* Wl = z == 0 ? WlK : z == 1 ? WlV : WlQ;
    const ushort* BH = (z == 2) ? Xmh : Xh;
    const ushort* BL = (z == 2) ? Xml : Xl;
    const float* bias = z == 0 ? k_b : z == 1 ? v_b : q_b;
    float* out = z == 0 ? Kbuf : z == 1 ? Vbuf : Qm;
    int bias_start = (z == 2) ? NP : PIX;            // pos rows get bias
    int m0 = blockIdx.x * 128, n0 = blockIdx.y * 64;

    int tid = threadIdx.x, wid = tid >> 6, lane = tid & 63;
    int wm = wid >> 1, wn = wid & 1;

    const char* gsrc[6];
    int ldsoff[6];
#pragma unroll
    for (int i = 0; i < 6; ++i) {
        int g = wid * 6 + i;
        const ushort* src; int r16; int off;
        if (g < 8)       { src = Wh; r16 = (m0 >> 4) + g;        off = g * 1024; }
        else if (g < 16) { src = Wl; r16 = (m0 >> 4) + (g - 8);  off = 8192 + (g - 8) * 1024; }
        else if (g < 20) { src = BH; r16 = (n0 >> 4) + (g - 16); off = 16384 + (g - 16) * 1024; }
        else             { src = BL; r16 = (n0 >> 4) + (g - 20); off = 20480 + (g - 20) * 1024; }
        gsrc[i] = (const char*)src + ((size_t)r16 * 64 * 1024) + lane * 16;
        ldsoff[i] = off;
    }

    f32x4 acc[4][2];
#pragma unroll
    for (int a = 0; a < 4; ++a)
#pragma unroll
        for (int b = 0; b < 2; ++b) acc[a][b] = (f32x4)0.f;

#pragma unroll
    for (int i = 0; i < 6; ++i)
        __builtin_amdgcn_global_load_lds((as1c_void*)(gsrc[i]),
                                         (as3_void*)(smem + ldsoff[i]), 16, 0, 0);
#pragma unroll
    for (int i = 0; i < 6; ++i)
        __builtin_amdgcn_global_load_lds((as1c_void*)(gsrc[i] + 1024),
                                         (as3_void*)(smem + BUFB + ldsoff[i]), 16, 0, 0);
    asm volatile("s_waitcnt vmcnt(6)" ::: "memory");   // tile 0 complete
    __builtin_amdgcn_s_barrier();
    asm volatile("" ::: "memory");

    for (int t = 0; t < 64; ++t) {
        char* rbuf = smem + (t % 3) * BUFB;
        if (t < 62) {
            char* wbuf = smem + ((t + 2) % 3) * BUFB;
#pragma unroll
            for (int i = 0; i < 6; ++i)
                __builtin_amdgcn_global_load_lds((as1c_void*)(gsrc[i] + (size_t)(t + 2) * 1024),
                                                 (as3_void*)(wbuf + ldsoff[i]), 16, 0, 0);
        }

        short8 ah[4], al[4];
#pragma unroll
        for (int fm = 0; fm < 4; ++fm) {
            int s = wm * 4 + fm;
            ah[fm] = *(const short8*)(rbuf + s * 1024 + lane * 16);
            al[fm] = *(const short8*)(rbuf + 8192 + s * 1024 + lane * 16);
        }
        short8 bh[2], bl[2];
#pragma unroll
        for (int fn = 0; fn < 2; ++fn) {
            int s = wn * 2 + fn;
            bh[fn] = *(const short8*)(rbuf + 16384 + s * 1024 + lane * 16);
            bl[fn] = *(const short8*)(rbuf + 20480 + s * 1024 + lane * 16);
        }
#pragma unroll
        for (int fn = 0; fn < 2; ++fn)
#pragma unroll
            for (int fm = 0; fm < 4; ++fm) {
                acc[fm][fn] = __builtin_amdgcn_mfma_f32_16x16x32_bf16(ah[fm], bh[fn], acc[fm][fn], 0, 0, 0);
                acc[fm][fn] = __builtin_amdgcn_mfma_f32_16x16x32_bf16(ah[fm], bl[fn], acc[fm][fn], 0, 0, 0);
                acc[fm][fn] = __builtin_amdgcn_mfma_f32_16x16x32_bf16(al[fm], bh[fn], acc[fm][fn], 0, 0, 0);
            }

        if (t < 62) asm volatile("s_waitcnt vmcnt(6)" ::: "memory");
        else        asm volatile("s_waitcnt vmcnt(0)" ::: "memory");
        __builtin_amdgcn_s_barrier();
        asm volatile("" ::: "memory");
    }

#pragma unroll
    for (int fm = 0; fm < 4; ++fm) {
        int mg = m0 + wm * 64 + fm * 16 + (lane >> 4) * 4;
        float4 bv = *(const float4*)(bias + mg);
#pragma unroll
        for (int fn = 0; fn < 2; ++fn) {
            int ng = n0 + wn * 32 + fn * 16 + (lane & 15);
            f32x4 o = acc[fm][fn];
            if (ng >= bias_start) { o[0] += bv.x; o[1] += bv.y; o[2] += bv.z; o[3] += bv.w; }
            *(f32x4*)(out + (size_t)ng * CDIM + mg) = o;
        }
    }
}

// ---------------------------------------------------------------------------
// POSS[p][h][t] = (Qm[p]+Qm[NP]) . Kbuf[PIX+t]  on h-slice (pos scores)
__global__ __launch_bounds__(256) void poss_k(const float* __restrict__ Kbuf,
                                              const float* __restrict__ Qm,
                                              float* __restrict__ POSS) {
    __shared__ float qsl[4 * HD];
    int pb = blockIdx.x * 4, h = blockIdx.y, tid = threadIdx.x;
    qsl[tid] = Qm[(size_t)(pb + (tid >> 6)) * CDIM + h * HD + (tid & 63)]
             + Qm[(size_t)NP * CDIM + h * HD + (tid & 63)];
    __syncthreads();
    if (tid < 200) {
        int pp = tid / 50, t = tid % 50;
        const float* kp = Kbuf + (size_t)(PIX + t) * CDIM + h * HD;
        const float* q = &qsl[pp * HD];
        float dot = 0.f;
#pragma unroll
        for (int d = 0; d < HD; d += 4) {
            float4 kv = *(const float4*)&kp[d];
            dot += kv.x * q[d] + kv.y * q[d + 1] + kv.z * q[d + 2] + kv.w * q[d + 3];
        }
        POSS[(size_t)(pb + pp) * (NHEAD * NTOK) + h * NTOK + t] = dot;
    }
}

// ---------------------------------------------------------------------------
// TW[j][c] = (txt_j/||txt_j||) . out_w[:,c];  cconst[j] = (txt_j/||..||) . out_b
// (round-10/13 verified configuration: grid (45, 8))
__global__ __launch_bounds__(256) void txtw_k(
    const float* __restrict__ txt, const float* __restrict__ out_w, const float* __restrict__ out_b,
    float* __restrict__ TW, float* __restrict__ cconst)
{
    __shared__ float ts[OUTD];
    __shared__ float red[256], redb[256];
    int j = blockIdx.x, cb = blockIdx.y, tid = threadIdx.x;

    float n2 = 0.f, db = 0.f;
    for (int o = tid; o < OUTD; o += 256) {
        float tv = txt[(size_t)j * OUTD + o];
        ts[o] = tv;
        n2 += tv * tv;
        db += tv * out_b[o];
    }
    red[tid] = n2; redb[tid] = db;
    __syncthreads();
    for (int s = 128; s > 0; s >>= 1) {
        if (tid < s) { red[tid] += red[tid + s]; redb[tid] += redb[tid + s]; }
        __syncthreads();
    }
    float inv = 1.f / sqrtf(red[0]);

    int c = cb * 256 + tid;
    float acc = 0.f;
    for (int o = 0; o < OUTD; ++o)
        acc += ts[o] * out_w[(size_t)o * CDIM + c];
    TW[(size_t)j * CDIM + c] = acc * inv;
    if (cb == 0 && tid == 0) cconst[j] = redb[0] * inv;
}

// ---------------------------------------------------------------------------
// TV[col][h*NTXT+j] = sum_d TW[j][h*64+d] * V[col][h*64+d]
__global__ __launch_bounds__(256) void tv_k(
    const float* __restrict__ TW, const float* __restrict__ Vbuf, float* __restrict__ TV)
{
    __shared__ float TWs[NTXT * HD];
    __shared__ float Vs[8 * HD];
    int cg = blockIdx.x, h = blockIdx.y, tid = threadIdx.x;
    int c0 = cg * 8;

    for (int idx = tid; idx < NTXT * HD; idx += 256) {
        int j = idx / HD, d = idx % HD;
        TWs[idx] = TW[(size_t)j * CDIM + h * HD + d];
    }
    for (int idx = tid; idx < 8 * HD; idx += 256) {
        int c = idx / HD, d = idx % HD;
        int col = c0 + c;
        Vs[idx] = (col < NKV) ? Vbuf[(size_t)col * CDIM + h * HD + d] : 0.f;
    }
    __syncthreads();

    for (int o = tid; o < 8 * NTXT; o += 256) {
        int c = o / NTXT, j = o % NTXT;
        int col = c0 + c;
        if (col >= NKV) continue;
        float acc = 0.f;
#pragma unroll
        for (int d = 0; d < HD; d += 4) {
            float4 tw = *(const float4*)&TWs[j * HD + d];
            float4 vv = *(const float4*)&Vs[c * HD + d];
            acc += tw.x * vv.x + tw.y * vv.y + tw.z * vv.z + tw.w * vv.w;
        }
        TV[(size_t)col * HJ + h * NTXT + j] = acc;
    }
}

// ---------------------------------------------------------------------------
// Fused per-(patch, 8-head-slice) scores + softmax + folded pooling, v3.
__global__ __launch_bounds__(384) void attn_fused_k(
    const float* __restrict__ Kbuf, const float* __restrict__ Qm,
    const float* __restrict__ TV, const float* __restrict__ POSS,
    float* __restrict__ pooledHJ)
{
    __shared__ float qs[8 * HD];       // q slice for 8 heads
    __shared__ float scf[8][NTOK];     // feature scores -> probs after softmax
    __shared__ float scp[8][NTOK];     // pos scores (from POSS)
    __shared__ int win[49];

    int flat = blockIdx.x;
    int s = (flat & 7) >> 1;
    int p = (flat >> 3) * 2 + (flat & 1);
    int h0 = s * 8;
    int pi = p / WO, pj = p % WO;
    int tid = threadIdx.x;

    if (tid < 128) {
        float4 a = *(const float4*)(Qm + (size_t)p * CDIM + h0 * HD + tid * 4);
        float4 b = *(const float4*)(Qm + (size_t)NP * CDIM + h0 * HD + tid * 4);
        a.x += b.x; a.y += b.y; a.z += b.z; a.w += b.w;
        *(float4*)&qs[tid * 4] = a;
    }
    if (tid < 49)
        win[tid] = (pi + tid / 7) * WF + (pj + tid % 7);
    for (int u = tid; u < 8 * NTOK; u += 384)
        scp[u / NTOK][u % NTOK] = POSS[(size_t)p * (NHEAD * NTOK) + h0 * NTOK + u];
    __syncthreads();

    // 392 feature dots (h, t=tt+1, row=win[tt]); 24 groups x 17 iters, stride-24.
    int grp = tid >> 4, gl = tid & 15;
    for (int i = 0; i < 17; ++i) {
        int pair = i * 24 + grp;
        if (pair < 392) {
            int h = pair / 49, tt = pair % 49;
            float4 kv = *(const float4*)(Kbuf + (size_t)win[tt] * CDIM + (h0 + h) * HD + gl * 4);
            float4 qv = *(const float4*)&qs[h * HD + gl * 4];
            float d = kv.x * qv.x + kv.y * qv.y + kv.z * qv.z + kv.w * qv.w;
            d += __shfl_xor(d, 1);
            d += __shfl_xor(d, 2);
            d += __shfl_xor(d, 4);
            d += __shfl_xor(d, 8);
            if (gl == 0) scf[h][tt + 1] = d;
        }
    }
    __syncthreads();

    // parallel softmax: group grp<8 = head, lanes cover tokens {gl, gl+16, gl+32, gl+48}
    if (tid < 128) {
        int h = grp;
        float sloc = 0.f;
#pragma unroll
        for (int i = 0; i < 4; ++i) {
            int t = gl + 16 * i;
            if (t >= 1 && t < NTOK) sloc += scf[h][t];
        }
        sloc += __shfl_xor(sloc, 1); sloc += __shfl_xor(sloc, 2);
        sloc += __shfl_xor(sloc, 4); sloc += __shfl_xor(sloc, 8);
        float s0 = sloc * (1.f / 49.f);

        float sc[4];
        float mloc = -1e30f;
#pragma unroll
        for (int i = 0; i < 4; ++i) {
            int t = gl + 16 * i;
            if (t < NTOK) {
                float base = (t == 0) ? s0 : scf[h][t];
                sc[i] = (base + scp[h][t]) * 0.125f;
                mloc = fmaxf(mloc, sc[i]);
            }
        }
        mloc = fmaxf(mloc, __shfl_xor(mloc, 1)); mloc = fmaxf(mloc, __shfl_xor(mloc, 2));
        mloc = fmaxf(mloc, __shfl_xor(mloc, 4)); mloc = fmaxf(mloc, __shfl_xor(mloc, 8));

        float ev[4];
        float eloc = 0.f;
#pragma unroll
        for (int i = 0; i < 4; ++i) {
            int t = gl + 16 * i;
            if (t < NTOK) { ev[i] = expf(sc[i] - mloc); eloc += ev[i]; }
        }
        eloc += __shfl_xor(eloc, 1); eloc += __shfl_xor(eloc, 2);
        eloc += __shfl_xor(eloc, 4); eloc += __shfl_xor(eloc, 8);
        float inv = 1.f / eloc;
#pragma unroll
        for (int i = 0; i < 4; ++i) {
            int t = gl + 16 * i;
            if (t < NTOK) scf[h][t] = ev[i] * inv;
        }
    }
    __syncthreads();

    // folded pooling for this slice's o-window (contiguous, coalesced)
    if (tid < 360) {
        int o = s * 360 + tid;
        int hloc = tid / 45;
        const float* apr = &scf[hloc][0];
        float lacc = 0.f, macc = 0.f;
#pragma unroll 7
        for (int t = 1; t < NTOK; ++t) {
            float a = apr[t];
            float v1 = TV[(size_t)win[t - 1] * HJ + o];
            float v2 = TV[(size_t)(PIX + t) * HJ + o];
            lacc += a * (v1 + v2);
            macc += v1;
        }
        float a0 = apr[0];
        lacc += a0 * (macc * (1.f / 49.f) + TV[(size_t)PIX * HJ + o]);
        pooledHJ[(size_t)p * HJ + o] = lacc;
    }
}

// ---------------------------------------------------------------------------
// finish: reduce pooledHJ over heads, add cconst, argmax -> bucket
__global__ __launch_bounds__(64) void finish_k(const float* __restrict__ pooledHJ,
                                               const float* __restrict__ cconst,
                                               int* __restrict__ bucket) {
    __shared__ float lg[NTXT];
    int p = blockIdx.x, lane = threadIdx.x;
    if (lane < NTXT) {
        float s = cconst[lane];
        const float* row = pooledHJ + (size_t)p * HJ;
#pragma unroll 8
        for (int h = 0; h < NHEAD; ++h) s += row[h * NTXT + lane];
        lg[lane] = s;
    }
    __syncthreads();
    if (lane == 0) {
        float best = lg[0]; int bi = 0;
        for (int j2 = 1; j2 < NTXT; ++j2)
            if (lg[j2] > best) { best = lg[j2]; bi = j2; }
        int bk = 0;
        const int bounds[5] = {8, 15, 22, 29, 36};
#pragma unroll
        for (int u = 0; u < 5; ++u) bk += (bi >= bounds[u]) ? 1 : 0;
        bucket[p] = bk;
    }
}

// ---------------------------------------------------------------------------
// votefill: per-output vote conv + argmax + fill (strided bucket load, r15 fix).
__global__ __launch_bounds__(256) void votefill_k(const int* __restrict__ bucket,
                                                  float* __restrict__ out) {
    const int HALF = OUTD * PIX;
    __shared__ int bk[NP];
    int tid = threadIdx.x;
    int base = blockIdx.x * 256;
    if (base + 255 >= HALF) {   // block touches batch-1 half: need buckets
        for (int i = tid; i < NP; i += 256) bk[i] = bucket[i];
        __syncthreads();
    }
    int idx = base + tid;
    if (idx >= 2 * HALF) return;
    if (idx < HALF) { out[idx] = 0.f; return; }
    int pix = (idx - HALF) % PIX;
    int y = pix / WF, x = pix % WF;
    int cnt[6] = {0, 0, 0, 0, 0, 0};
    int i0 = (y - 6 < 0) ? 0 : y - 6;
    int i1 = (y > HO - 1) ? HO - 1 : y;
    int j0 = (x - 6 < 0) ? 0 : x - 6;
    int j1 = (x > WO - 1) ? WO - 1 : x;
    for (int i = i0; i <= i1; ++i)
        for (int j = j0; j <= j1; ++j)
            cnt[bk[i * WO + j]]++;
    int best = cnt[0], bi = 0;
#pragma unroll
    for (int ch = 1; ch < 6; ++ch)
        if (cnt[ch] > best) { best = cnt[ch]; bi = ch; }
    out[idx] = (bi > 0) ? 0.044194173824159216f : 0.f;   // 1/sqrt(512)
}

// ---------------------------------------------------------------------------
extern "C" void kernel_launch(void* const* d_in, const int* in_sizes, int n_in,
                              void* d_out, int out_size, void* d_ws, size_t ws_size,
                              hipStream_t stream) {
    const float* imgf = (const float*)d_in[0];
    const float* txt  = (const float*)d_in[1];
    const float* pos  = (const float*)d_in[2];
    const float* q_w  = (const float*)d_in[3];
    const float* q_b  = (const float*)d_in[4];
    const float* k_w  = (const float*)d_in[5];
    const float* k_b  = (const float*)d_in[6];
    const float* v_w  = (const float*)d_in[7];
    const float* v_b  = (const float*)d_in[8];
    const float* o_w  = (const float*)d_in[9];
    const float* o_b  = (const float*)d_in[10];

    const float* feat1 = imgf + (size_t)1 * CDIM * PIX;   // only batch B-1=1 matters

    float* ws = (float*)d_ws;
    float* Kbuf  = ws;                                   // 640*2048
    float* Vbuf  = Kbuf + (size_t)NROWS * CDIM;
    float* Qm    = Vbuf + (size_t)NROWS * CDIM;          // 384*2048 (row 324 = pos0 proj)
    float* mf    = Qm + (size_t)NQROWS * CDIM;           // 2048*324
    float* TW    = mf + (size_t)CDIM * NP;               // 45*2048
    float* cconst = TW + (size_t)NTXT * CDIM;            // 64
    float* TV    = cconst + 64;                          // 626*1440
    float* pooledHJ = TV + (size_t)NKV * HJ;             // 324*1440
    float* POSS  = pooledHJ + (size_t)NP * HJ;           // 324*1600
    int*   bucket = (int*)(POSS + (size_t)NP * NHEAD * NTOK);  // 324
    float* endf   = (float*)(bucket + NP);
    size_t foff = (size_t)(endf - ws);
    foff = (foff + 3) & ~(size_t)3;                      // 16B align
    ushort* WhK = (ushort*)(ws + foff);                  // each 2048*2048
    ushort* WlK = WhK + (size_t)CDIM * CDIM;
    ushort* WhV = WlK + (size_t)CDIM * CDIM;
    ushort* WlV = WhV + (size_t)CDIM * CDIM;
    ushort* WhQ = WlV + (size_t)CDIM * CDIM;
    ushort* WlQ = WhQ + (size_t)CDIM * CDIM;
    ushort* Xh  = WlQ + (size_t)CDIM * CDIM;             // 640*2048
    ushort* Xl  = Xh + (size_t)NROWS * CDIM;
    ushort* Xmh = Xl + (size_t)NROWS * CDIM;             // 384*2048
    ushort* Xml = Xmh + (size_t)NQROWS * CDIM;

    split_w_k<<<dim3(6144), dim3(256), 0, stream>>>(k_w, v_w, q_w, WhK, WlK, WhV, WlV, WhQ, WlQ);
    mfeat_k<<<dim3(CDIM), dim3(64), 0, stream>>>(feat1, mf);
    splitx_k<<<dim3(608), dim3(256), 0, stream>>>(feat1, pos, mf, Xh, Xl, Xmh, Xml);
    gemm_bf16_k<<<dim3(16, 10, 3), dim3(256), 0, stream>>>(WhK, WlK, WhV, WlV, WhQ, WlQ,
                                                           Xh, Xl, Xmh, Xml,
                                                           k_b, v_b, q_b, Kbuf, Vbuf, Qm);
    poss_k<<<dim3(81, 32), dim3(256), 0, stream>>>(Kbuf, Qm, POSS);
    txtw_k<<<dim3(NTXT, 8), dim3(256), 0, stream>>>(txt, o_w, o_b, TW, cconst);
    tv_k<<<dim3(79, 32), dim3(256), 0, stream>>>(TW, Vbuf, TV);
    attn_fused_k<<<dim3(NP * 4), dim3(384), 0, stream>>>(Kbuf, Qm, TV, POSS, pooledHJ);
    finish_k<<<dim3(NP), dim3(64), 0, stream>>>(pooledHJ, cconst, bucket);
    votefill_k<<<dim3(2304), dim3(256), 0, stream>>>(bucket, (float*)d_out);
}

// Round 17
// 193.296 us; speedup vs baseline: 1.0329x; 1.0329x over previous
//
#include <hip/hip_runtime.h>
#include <math.h>

#define CDIM 2048
#define HF 24
#define WF 24
#define PIX 576
#define HO 18
#define WO 18
#define NP 324
#define NHEAD 32
#define HD 64
#define NTOK 50
#define NTXT 45
#define OUTD 512
#define NKV 626
#define HJ (NHEAD * NTXT)   // 1440
#define NROWS 640           // padded B rows: 576 pixels + 50 pos + 14 zero

typedef __attribute__((ext_vector_type(8))) short short8;
typedef __attribute__((ext_vector_type(4))) float f32x4;
typedef __attribute__((address_space(1))) const void as1c_void;
typedef __attribute__((address_space(3))) void as3_void;

__device__ inline unsigned bf16rn(float x) {
    unsigned u = __float_as_uint(x);
    return (u + 0x7FFFu + ((u >> 16) & 1u)) >> 16;
}
__device__ inline float bf16tof(unsigned h) { return __uint_as_float(h << 16); }

// Fragment-tile global layout (ushort element offset): tile (row>>4, k>>5) is
// 512 contiguous ushorts (1KB); global_load_lds reads it as lane*16B bursts.
__device__ inline size_t frag_off(int row, int k) {
    return (size_t)(((row >> 4) * 64 + (k >> 5)) * 512)
         + (size_t)(((k & 31) >> 3) * 128 + (row & 15) * 8 + (k & 7));
}

// ---------------------------------------------------------------------------
// Split the 3 weight matrices into hi/lo bf16, fragment-tile layout.
// One wave per 16x32 tile: contiguous 1KB tile written by one wave.
__global__ __launch_bounds__(256) void split_w_k(
    const float* __restrict__ kw, const float* __restrict__ vw, const float* __restrict__ qw,
    ushort* __restrict__ WhK, ushort* __restrict__ WlK,
    ushort* __restrict__ WhV, ushort* __restrict__ WlV,
    ushort* __restrict__ WhQ, ushort* __restrict__ WlQ) {
    int gw = blockIdx.x * 4 + (threadIdx.x >> 6);   // global tile id, 3*8192 total
    int lane = threadIdx.x & 63;
    int sel = gw >> 13;                             // matrix (8192 tiles each)
    int tl = gw & 8191;
    int m16 = tl >> 6;                              // row-tile (m/16)
    int kt = tl & 63;                               // k-tile (k/32)
    const float* src = sel == 0 ? kw : sel == 1 ? vw : qw;
    ushort* dh = sel == 0 ? WhK : sel == 1 ? WhV : WhQ;
    ushort* dl = sel == 0 ? WlK : sel == 1 ? WlV : WlQ;

    int row = m16 * 16 + (lane & 15);
    int k = kt * 32 + (lane >> 4) * 8;
    const float* sp = src + (size_t)row * CDIM + k;
    float4 a = *(const float4*)sp;
    float4 b = *(const float4*)(sp + 4);
    float xs[8] = {a.x, a.y, a.z, a.w, b.x, b.y, b.z, b.w};
    short8 hv, lv;
#pragma unroll
    for (int i = 0; i < 8; ++i) {
        unsigned hh = bf16rn(xs[i]);
        hv[i] = (short)hh;
        lv[i] = (short)bf16rn(xs[i] - bf16tof(hh));
    }
    size_t to = (size_t)tl * 512 + lane * 8;
    *(short8*)(dh + to) = hv;
    *(short8*)(dl + to) = lv;
}

// ---------------------------------------------------------------------------
// Merged: transpose+split feat1 (blocks 0..287) and pos rows (blocks 288..415).
__global__ __launch_bounds__(256) void splitx_k(const float* __restrict__ feat1,
                                                const float* __restrict__ pos,
                                                ushort* __restrict__ Xh, ushort* __restrict__ Xl) {
    int b = blockIdx.x, tid = threadIdx.x;
    if (b < 288) {
        __shared__ float tile[64][65];
        int n0 = (b % 9) * 64, c0 = (b / 9) * 64;
#pragma unroll
        for (int i = 0; i < 16; ++i) {
            int idx = tid + i * 256;
            int cc = idx >> 6, nn = idx & 63;
            tile[cc][nn] = feat1[(size_t)(c0 + cc) * PIX + n0 + nn];
        }
        __syncthreads();
#pragma unroll
        for (int i = 0; i < 16; ++i) {
            int idx = tid + i * 256;
            int nn = idx >> 6, cc = idx & 63;
            float x = tile[cc][nn];
            unsigned hh = bf16rn(x);
            size_t fo = frag_off(n0 + nn, c0 + cc);
            Xh[fo] = (ushort)hh;
            Xl[fo] = (ushort)bf16rn(x - bf16tof(hh));
        }
    } else {
        int g = (b - 288) * 256 + tid;              // 32768 threads, 4 elems each
        int r = g >> 9;                              // 0..63
        int c = (g & 511) * 4;
        float4 v = make_float4(0.f, 0.f, 0.f, 0.f);
        if (r < 50) v = *(const float4*)(pos + (size_t)r * CDIM + c);
        float xs[4] = {v.x, v.y, v.z, v.w};
        ushort h[4], l[4];
#pragma unroll
        for (int i = 0; i < 4; ++i) {
            unsigned hh = bf16rn(xs[i]);
            h[i] = (ushort)hh;
            l[i] = (ushort)bf16rn(xs[i] - bf16tof(hh));
        }
        size_t fo = frag_off(576 + r, c);
        *(ushort4*)(Xh + fo) = make_ushort4(h[0], h[1], h[2], h[3]);
        *(ushort4*)(Xl + fo) = make_ushort4(l[0], l[1], l[2], l[3]);
    }
}

// ---------------------------------------------------------------------------
// Split-bf16 MFMA GEMM, 3-buffer depth-2 pipeline, coalesced frag-tile staging
// (round-10 verified-best configuration: 128m x 64n, 2 blocks/CU). FROZEN.
#define BUFB 24576
__global__ __launch_bounds__(256, 2) void gemm_bf16_k(
    const ushort* __restrict__ WhK, const ushort* __restrict__ WlK,
    const ushort* __restrict__ WhV, const ushort* __restrict__ WlV,
    const ushort* __restrict__ WhQ, const ushort* __restrict__ WlQ,
    const ushort* __restrict__ Xh, const ushort* __restrict__ Xl,
    const float* __restrict__ k_b, const float* __restrict__ v_b, const float* __restrict__ q_b,
    float* __restrict__ Kbuf, float* __restrict__ Vbuf, float* __restrict__ Qfull)
{
    __shared__ char smem[3 * BUFB];   // 72 KB: 3 rotating tile buffers
    int z = blockIdx.z;
    const ushort* Wh = z == 0 ? WhK : z == 1 ? WhV : WhQ;
    const ushort* Wl = z == 0 ? WlK : z == 1 ? WlV : WlQ;
    const float* bias = z == 0 ? k_b : z == 1 ? v_b : q_b;
    float* out = z == 0 ? Kbuf : z == 1 ? Vbuf : Qfull;
    int m0 = blockIdx.x * 128, n0 = blockIdx.y * 64;

    int tid = threadIdx.x, wid = tid >> 6, lane = tid & 63;
    int wm = wid >> 1, wn = wid & 1;

    const char* gsrc[6];
    int ldsoff[6];
#pragma unroll
    for (int i = 0; i < 6; ++i) {
        int g = wid * 6 + i;
        const ushort* src; int r16; int off;
        if (g < 8)       { src = Wh; r16 = (m0 >> 4) + g;        off = g * 1024; }
        else if (g < 16) { src = Wl; r16 = (m0 >> 4) + (g - 8);  off = 8192 + (g - 8) * 1024; }
        else if (g < 20) { src = Xh; r16 = (n0 >> 4) + (g - 16); off = 16384 + (g - 16) * 1024; }
        else             { src = Xl; r16 = (n0 >> 4) + (g - 20); off = 20480 + (g - 20) * 1024; }
        gsrc[i] = (const char*)src + ((size_t)r16 * 64 * 1024) + lane * 16;
        ldsoff[i] = off;
    }

    f32x4 acc[4][2];
#pragma unroll
    for (int a = 0; a < 4; ++a)
#pragma unroll
        for (int b = 0; b < 2; ++b) acc[a][b] = (f32x4)0.f;

#pragma unroll
    for (int i = 0; i < 6; ++i)
        __builtin_amdgcn_global_load_lds((as1c_void*)(gsrc[i]),
                                         (as3_void*)(smem + ldsoff[i]), 16, 0, 0);
#pragma unroll
    for (int i = 0; i < 6; ++i)
        __builtin_amdgcn_global_load_lds((as1c_void*)(gsrc[i] + 1024),
                                         (as3_void*)(smem + BUFB + ldsoff[i]), 16, 0, 0);
    asm volatile("s_waitcnt vmcnt(6)" ::: "memory");   // tile 0 complete
    __builtin_amdgcn_s_barrier();
    asm volatile("" ::: "memory");

    for (int t = 0; t < 64; ++t) {
        char* rbuf = smem + (t % 3) * BUFB;
        if (t < 62) {
            char* wbuf = smem + ((t + 2) % 3) * BUFB;
#pragma unroll
            for (int i = 0; i < 6; ++i)
                __builtin_amdgcn_global_load_lds((as1c_void*)(gsrc[i] + (size_t)(t + 2) * 1024),
                                                 (as3_void*)(wbuf + ldsoff[i]), 16, 0, 0);
        }

        short8 ah[4], al[4];
#pragma unroll
        for (int fm = 0; fm < 4; ++fm) {
            int s = wm * 4 + fm;
            ah[fm] = *(const short8*)(rbuf + s * 1024 + lane * 16);
            al[fm] = *(const short8*)(rbuf + 8192 + s * 1024 + lane * 16);
        }
        short8 bh[2], bl[2];
#pragma unroll
        for (int fn = 0; fn < 2; ++fn) {
            int s = wn * 2 + fn;
            bh[fn] = *(const short8*)(rbuf + 16384 + s * 1024 + lane * 16);
            bl[fn] = *(const short8*)(rbuf + 20480 + s * 1024 + lane * 16);
        }
#pragma unroll
        for (int fn = 0; fn < 2; ++fn)
#pragma unroll
            for (int fm = 0; fm < 4; ++fm) {
                acc[fm][fn] = __builtin_amdgcn_mfma_f32_16x16x32_bf16(ah[fm], bh[fn], acc[fm][fn], 0, 0, 0);
                acc[fm][fn] = __builtin_amdgcn_mfma_f32_16x16x32_bf16(ah[fm], bl[fn], acc[fm][fn], 0, 0, 0);
                acc[fm][fn] = __builtin_amdgcn_mfma_f32_16x16x32_bf16(al[fm], bh[fn], acc[fm][fn], 0, 0, 0);
            }

        if (t < 62) asm volatile("s_waitcnt vmcnt(6)" ::: "memory");
        else        asm volatile("s_waitcnt vmcnt(0)" ::: "memory");
        __builtin_amdgcn_s_barrier();
        asm volatile("" ::: "memory");
    }

#pragma unroll
    for (int fm = 0; fm < 4; ++fm) {
        int mg = m0 + wm * 64 + fm * 16 + (lane >> 4) * 4;
        float4 bv = *(const float4*)(bias + mg);
#pragma unroll
        for (int fn = 0; fn < 2; ++fn) {
            int ng = n0 + wn * 32 + fn * 16 + (lane & 15);
            f32x4 o = acc[fm][fn];
            if (ng >= PIX) { o[0] += bv.x; o[1] += bv.y; o[2] += bv.z; o[3] += bv.w; }
            *(f32x4*)(out + (size_t)ng * CDIM + mg) = o;
        }
    }
}

// ---------------------------------------------------------------------------
// Separable 7x7 window mean, pass 1: cm[i*18+j][c] = sum_{dj<7} Qfull[i*24+j+dj][c]
__global__ __launch_bounds__(256) void colmean_k(const float* __restrict__ Qfull,
                                                 float* __restrict__ cm) {
    int i = blockIdx.x;
    int c = blockIdx.y * 1024 + threadIdx.x * 4;
    float4 v[24];
#pragma unroll
    for (int x = 0; x < 24; ++x)
        v[x] = *(const float4*)(Qfull + (size_t)(i * WF + x) * CDIM + c);
#pragma unroll
    for (int j = 0; j < 18; ++j) {
        float4 s = v[j];
#pragma unroll
        for (int d = 1; d < 7; ++d) {
            s.x += v[j + d].x; s.y += v[j + d].y; s.z += v[j + d].z; s.w += v[j + d].w;
        }
        *(float4*)(cm + (size_t)(i * 18 + j) * CDIM + c) = s;
    }
}

// Pass 2: Qm[pi*18+pj][c] = (sum_{di<7} cm[(pi+di)*18+pj][c]) / 49 + Qfull[576][c]
__global__ __launch_bounds__(256) void qmean2_k(const float* __restrict__ cm,
                                                const float* __restrict__ Qfull,
                                                float* __restrict__ Qm) {
    int pj = blockIdx.x;
    int c = blockIdx.y * 1024 + threadIdx.x * 4;
    float4 p0 = *(const float4*)(Qfull + (size_t)PIX * CDIM + c);
    float4 v[24];
#pragma unroll
    for (int x = 0; x < 24; ++x)
        v[x] = *(const float4*)(cm + (size_t)(x * 18 + pj) * CDIM + c);
#pragma unroll
    for (int pi = 0; pi < 18; ++pi) {
        float4 s = v[pi];
#pragma unroll
        for (int d = 1; d < 7; ++d) {
            s.x += v[pi + d].x; s.y += v[pi + d].y; s.z += v[pi + d].z; s.w += v[pi + d].w;
        }
        float4 r;
        r.x = s.x * (1.f / 49.f) + p0.x;
        r.y = s.y * (1.f / 49.f) + p0.y;
        r.z = s.z * (1.f / 49.f) + p0.z;
        r.w = s.w * (1.f / 49.f) + p0.w;
        *(float4*)(Qm + (size_t)(pi * 18 + pj) * CDIM + c) = r;
    }
}

// ---------------------------------------------------------------------------
// POSS[p][h][t] = Qm[p][h-slice] . Kbuf[PIX+t][h-slice]   (pos scores, all patches)
__global__ __launch_bounds__(256) void poss_k(const float* __restrict__ Kbuf,
                                              const float* __restrict__ Qm,
                                              float* __restrict__ POSS) {
    __shared__ float qsl[4 * HD];
    int pb = blockIdx.x * 4, h = blockIdx.y, tid = threadIdx.x;
    qsl[tid] = Qm[(size_t)(pb + (tid >> 6)) * CDIM + h * HD + (tid & 63)];
    __syncthreads();
    if (tid < 200) {
        int pp = tid / 50, t = tid % 50;
        const float* kp = Kbuf + (size_t)(PIX + t) * CDIM + h * HD;
        const float* q = &qsl[pp * HD];
        float dot = 0.f;
#pragma unroll
        for (int d = 0; d < HD; d += 4) {
            float4 kv = *(const float4*)&kp[d];
            dot += kv.x * q[d] + kv.y * q[d + 1] + kv.z * q[d + 2] + kv.w * q[d + 3];
        }
        POSS[(size_t)(pb + pp) * (NHEAD * NTOK) + h * NTOK + t] = dot;
    }
}

// ---------------------------------------------------------------------------
// TW[j][c] = (txt_j/||txt_j||) . out_w[:,c];  cconst[j] = (txt_j/||..||) . out_b
// (round-10 verified configuration: grid (45, 8))
__global__ __launch_bounds__(256) void txtw_k(
    const float* __restrict__ txt, const float* __restrict__ out_w, const float* __restrict__ out_b,
    float* __restrict__ TW, float* __restrict__ cconst)
{
    __shared__ float ts[OUTD];
    __shared__ float red[256], redb[256];
    int j = blockIdx.x, cb = blockIdx.y, tid = threadIdx.x;

    float n2 = 0.f, db = 0.f;
    for (int o = tid; o < OUTD; o += 256) {
        float tv = txt[(size_t)j * OUTD + o];
        ts[o] = tv;
        n2 += tv * tv;
        db += tv * out_b[o];
    }
    red[tid] = n2; redb[tid] = db;
    __syncthreads();
    for (int s = 128; s > 0; s >>= 1) {
        if (tid < s) { red[tid] += red[tid + s]; redb[tid] += redb[tid + s]; }
        __syncthreads();
    }
    float inv = 1.f / sqrtf(red[0]);

    int c = cb * 256 + tid;
    float acc = 0.f;
    for (int o = 0; o < OUTD; ++o)
        acc += ts[o] * out_w[(size_t)o * CDIM + c];
    TW[(size_t)j * CDIM + c] = acc * inv;
    if (cb == 0 && tid == 0) cconst[j] = redb[0] * inv;
}

// ---------------------------------------------------------------------------
// TV[col][h*NTXT+j] = sum_d TW[j][h*64+d] * V[col][h*64+d]
__global__ __launch_bounds__(256) void tv_k(
    const float* __restrict__ TW, const float* __restrict__ Vbuf, float* __restrict__ TV)
{
    __shared__ float TWs[NTXT * HD];
    __shared__ float Vs[8 * HD];
    int cg = blockIdx.x, h = blockIdx.y, tid = threadIdx.x;
    int c0 = cg * 8;

    for (int idx = tid; idx < NTXT * HD; idx += 256) {
        int j = idx / HD, d = idx % HD;
        TWs[idx] = TW[(size_t)j * CDIM + h * HD + d];
    }
    for (int idx = tid; idx < 8 * HD; idx += 256) {
        int c = idx / HD, d = idx % HD;
        int col = c0 + c;
        Vs[idx] = (col < NKV) ? Vbuf[(size_t)col * CDIM + h * HD + d] : 0.f;
    }
    __syncthreads();

    for (int o = tid; o < 8 * NTXT; o += 256) {
        int c = o / NTXT, j = o % NTXT;
        int col = c0 + c;
        if (col >= NKV) continue;
        float acc = 0.f;
#pragma unroll
        for (int d = 0; d < HD; d += 4) {
            float4 tw = *(const float4*)&TWs[j * HD + d];
            float4 vv = *(const float4*)&Vs[c * HD + d];
            acc += tw.x * vv.x + tw.y * vv.y + tw.z * vv.z + tw.w * vv.w;
        }
        TV[(size_t)col * HJ + h * NTXT + j] = acc;
    }
}

// ---------------------------------------------------------------------------
// Fused per-(patch, 8-head-slice) scores + softmax + folded pooling, v3.
__global__ __launch_bounds__(384) void attn_fused_k(
    const float* __restrict__ Kbuf, const float* __restrict__ Qm,
    const float* __restrict__ TV, const float* __restrict__ POSS,
    float* __restrict__ pooledHJ)
{
    __shared__ float qs[8 * HD];       // q slice for 8 heads
    __shared__ float scf[8][NTOK];     // feature scores -> probs after softmax
    __shared__ float scp[8][NTOK];     // pos scores (from POSS)
    __shared__ int win[49];

    int flat = blockIdx.x;
    int s = (flat & 7) >> 1;
    int p = (flat >> 3) * 2 + (flat & 1);
    int h0 = s * 8;
    int pi = p / WO, pj = p % WO;
    int tid = threadIdx.x;

    if (tid < 128)
        *(float4*)&qs[tid * 4] = *(const float4*)(Qm + (size_t)p * CDIM + h0 * HD + tid * 4);
    if (tid < 49)
        win[tid] = (pi + tid / 7) * WF + (pj + tid % 7);
    for (int u = tid; u < 8 * NTOK; u += 384)
        scp[u / NTOK][u % NTOK] = POSS[(size_t)p * (NHEAD * NTOK) + h0 * NTOK + u];
    __syncthreads();

    // 392 feature dots (h, t=tt+1, row=win[tt]); 24 groups x 17 iters, stride-24.
    int grp = tid >> 4, gl = tid & 15;
    for (int i = 0; i < 17; ++i) {
        int pair = i * 24 + grp;
        if (pair < 392) {
            int h = pair / 49, tt = pair % 49;
            float4 kv = *(const float4*)(Kbuf + (size_t)win[tt] * CDIM + (h0 + h) * HD + gl * 4);
            float4 qv = *(const float4*)&qs[h * HD + gl * 4];
            float d = kv.x * qv.x + kv.y * qv.y + kv.z * qv.z + kv.w * qv.w;
            d += __shfl_xor(d, 1);
            d += __shfl_xor(d, 2);
            d += __shfl_xor(d, 4);
            d += __shfl_xor(d, 8);
            if (gl == 0) scf[h][tt + 1] = d;
        }
    }
    __syncthreads();

    // parallel softmax: group grp<8 = head, lanes cover tokens {gl, gl+16, gl+32, gl+48}
    if (tid < 128) {
        int h = grp;
        float sloc = 0.f;
#pragma unroll
        for (int i = 0; i < 4; ++i) {
            int t = gl + 16 * i;
            if (t >= 1 && t < NTOK) sloc += scf[h][t];
        }
        sloc += __shfl_xor(sloc, 1); sloc += __shfl_xor(sloc, 2);
        sloc += __shfl_xor(sloc, 4); sloc += __shfl_xor(sloc, 8);
        float s0 = sloc * (1.f / 49.f);

        float sc[4];
        float mloc = -1e30f;
#pragma unroll
        for (int i = 0; i < 4; ++i) {
            int t = gl + 16 * i;
            if (t < NTOK) {
                float base = (t == 0) ? s0 : scf[h][t];
                sc[i] = (base + scp[h][t]) * 0.125f;
                mloc = fmaxf(mloc, sc[i]);
            }
        }
        mloc = fmaxf(mloc, __shfl_xor(mloc, 1)); mloc = fmaxf(mloc, __shfl_xor(mloc, 2));
        mloc = fmaxf(mloc, __shfl_xor(mloc, 4)); mloc = fmaxf(mloc, __shfl_xor(mloc, 8));

        float ev[4];
        float eloc = 0.f;
#pragma unroll
        for (int i = 0; i < 4; ++i) {
            int t = gl + 16 * i;
            if (t < NTOK) { ev[i] = expf(sc[i] - mloc); eloc += ev[i]; }
        }
        eloc += __shfl_xor(eloc, 1); eloc += __shfl_xor(eloc, 2);
        eloc += __shfl_xor(eloc, 4); eloc += __shfl_xor(eloc, 8);
        float inv = 1.f / eloc;
#pragma unroll
        for (int i = 0; i < 4; ++i) {
            int t = gl + 16 * i;
            if (t < NTOK) scf[h][t] = ev[i] * inv;
        }
    }
    __syncthreads();

    // folded pooling for this slice's o-window (contiguous, coalesced)
    if (tid < 360) {
        int o = s * 360 + tid;
        int hloc = tid / 45;
        const float* apr = &scf[hloc][0];
        float lacc = 0.f, macc = 0.f;
#pragma unroll 7
        for (int t = 1; t < NTOK; ++t) {
            float a = apr[t];
            float v1 = TV[(size_t)win[t - 1] * HJ + o];
            float v2 = TV[(size_t)(PIX + t) * HJ + o];
            lacc += a * (v1 + v2);
            macc += v1;
        }
        float a0 = apr[0];
        lacc += a0 * (macc * (1.f / 49.f) + TV[(size_t)PIX * HJ + o]);
        pooledHJ[(size_t)p * HJ + o] = lacc;
    }
}

// ---------------------------------------------------------------------------
// finish: reduce pooledHJ over heads, add cconst, argmax -> bucket
__global__ __launch_bounds__(64) void finish_k(const float* __restrict__ pooledHJ,
                                               const float* __restrict__ cconst,
                                               int* __restrict__ bucket) {
    __shared__ float lg[NTXT];
    int p = blockIdx.x, lane = threadIdx.x;
    if (lane < NTXT) {
        float s = cconst[lane];
        const float* row = pooledHJ + (size_t)p * HJ;
#pragma unroll 8
        for (int h = 0; h < NHEAD; ++h) s += row[h * NTXT + lane];
        lg[lane] = s;
    }
    __syncthreads();
    if (lane == 0) {
        float best = lg[0]; int bi = 0;
        for (int j2 = 1; j2 < NTXT; ++j2)
            if (lg[j2] > best) { best = lg[j2]; bi = j2; }
        int bk = 0;
        const int bounds[5] = {8, 15, 22, 29, 36};
#pragma unroll
        for (int u = 0; u < 5; ++u) bk += (bi >= bounds[u]) ? 1 : 0;
        bucket[p] = bk;
    }
}

// ---------------------------------------------------------------------------
__global__ void votes_k(const int* __restrict__ bucket, float* __restrict__ maxval) {
    __shared__ int bk[NP];
    int tid = threadIdx.x;
    if (tid < NP) bk[tid] = bucket[tid];
    __syncthreads();
    if (tid < PIX) {
        int y = tid / WF, x = tid % WF;
        int cnt[6] = {0, 0, 0, 0, 0, 0};
        int i0 = (y - 6 < 0) ? 0 : y - 6;
        int i1 = (y > HO - 1) ? HO - 1 : y;
        int j0 = (x - 6 < 0) ? 0 : x - 6;
        int j1 = (x > WO - 1) ? WO - 1 : x;
        for (int i = i0; i <= i1; ++i)
            for (int j = j0; j <= j1; ++j)
                cnt[bk[i * WO + j]]++;
        int best = cnt[0], bi = 0;
#pragma unroll
        for (int ch = 1; ch < 6; ++ch)
            if (cnt[ch] > best) { best = cnt[ch]; bi = ch; }
        maxval[tid] = (bi > 0) ? 0.044194173824159216f : 0.f;
    }
}

__global__ void fill_k(const float* __restrict__ maxval, float* __restrict__ out) {
    int idx = blockIdx.x * 256 + threadIdx.x;
    const int HALF = OUTD * PIX;
    if (idx >= 2 * HALF) return;
    out[idx] = (idx < HALF) ? 0.f : maxval[idx % PIX];
}

// ---------------------------------------------------------------------------
extern "C" void kernel_launch(void* const* d_in, const int* in_sizes, int n_in,
                              void* d_out, int out_size, void* d_ws, size_t ws_size,
                              hipStream_t stream) {
    const float* imgf = (const float*)d_in[0];
    const float* txt  = (const float*)d_in[1];
    const float* pos  = (const float*)d_in[2];
    const float* q_w  = (const float*)d_in[3];
    const float* q_b  = (const float*)d_in[4];
    const float* k_w  = (const float*)d_in[5];
    const float* k_b  = (const float*)d_in[6];
    const float* v_w  = (const float*)d_in[7];
    const float* v_b  = (const float*)d_in[8];
    const float* o_w  = (const float*)d_in[9];
    const float* o_b  = (const float*)d_in[10];

    const float* feat1 = imgf + (size_t)1 * CDIM * PIX;   // only batch B-1=1 matters

    float* ws = (float*)d_ws;
    float* Kbuf  = ws;                                   // 640*2048
    float* Vbuf  = Kbuf + (size_t)NROWS * CDIM;
    float* Qfull = Vbuf + (size_t)NROWS * CDIM;
    float* Qm    = Qfull + (size_t)NROWS * CDIM;         // 324*2048
    float* cm    = Qm + (size_t)NP * CDIM;               // 432*2048 (separable pass-1)
    float* TW    = cm + (size_t)432 * CDIM;              // 45*2048
    float* cconst = TW + (size_t)NTXT * CDIM;            // 64
    float* TV    = cconst + 64;                          // 626*1440
    float* pooledHJ = TV + (size_t)NKV * HJ;             // 324*1440
    float* POSS  = pooledHJ + (size_t)NP * HJ;           // 324*1600
    int*   bucket = (int*)(POSS + (size_t)NP * NHEAD * NTOK);  // 324
    float* maxval = (float*)(bucket + NP);               // 576
    size_t foff = (size_t)(maxval + 576 - ws);
    foff = (foff + 3) & ~(size_t)3;                      // 16B align
    ushort* WhK = (ushort*)(ws + foff);                  // each 2048*2048
    ushort* WlK = WhK + (size_t)CDIM * CDIM;
    ushort* WhV = WlK + (size_t)CDIM * CDIM;
    ushort* WlV = WhV + (size_t)CDIM * CDIM;
    ushort* WhQ = WlV + (size_t)CDIM * CDIM;
    ushort* WlQ = WhQ + (size_t)CDIM * CDIM;
    ushort* Xh  = WlQ + (size_t)CDIM * CDIM;             // 640*2048
    ushort* Xl  = Xh + (size_t)NROWS * CDIM;

    split_w_k<<<dim3(6144), dim3(256), 0, stream>>>(k_w, v_w, q_w, WhK, WlK, WhV, WlV, WhQ, WlQ);
    splitx_k<<<dim3(416), dim3(256), 0, stream>>>(feat1, pos, Xh, Xl);
    gemm_bf16_k<<<dim3(16, 10, 3), dim3(256), 0, stream>>>(WhK, WlK, WhV, WlV, WhQ, WlQ,
                                                           Xh, Xl, k_b, v_b, q_b, Kbuf, Vbuf, Qfull);
    colmean_k<<<dim3(24, 2), dim3(256), 0, stream>>>(Qfull, cm);
    qmean2_k<<<dim3(18, 2), dim3(256), 0, stream>>>(cm, Qfull, Qm);
    poss_k<<<dim3(81, 32), dim3(256), 0, stream>>>(Kbuf, Qm, POSS);
    txtw_k<<<dim3(NTXT, 8), dim3(256), 0, stream>>>(txt, o_w, o_b, TW, cconst);
    tv_k<<<dim3(79, 32), dim3(256), 0, stream>>>(TW, Vbuf, TV);
    attn_fused_k<<<dim3(NP * 4), dim3(384), 0, stream>>>(Kbuf, Qm, TV, POSS, pooledHJ);
    finish_k<<<dim3(NP), dim3(64), 0, stream>>>(pooledHJ, cconst, bucket);
    votes_k<<<dim3(1), dim3(576), 0, stream>>>(bucket, maxval);
    fill_k<<<dim3(2304), dim3(256), 0, stream>>>(maxval, (float*)d_out);
}